// Round 6
// baseline (476.114 us; speedup 1.0000x reference)
//
#include <hip/hip_runtime.h>

typedef unsigned short u16;
typedef float f32x4 __attribute__((ext_vector_type(4)));
typedef __bf16 bf16x8 __attribute__((ext_vector_type(8)));

__device__ __forceinline__ u16 f2bf(float f) {
  unsigned u = __float_as_uint(f);
  u += 0x7fffu + ((u >> 16) & 1u);
  return (u16)(u >> 16);
}

__device__ __forceinline__ f32x4 mfma16(bf16x8 a, bf16x8 b, f32x4 c) {
  return __builtin_amdgcn_mfma_f32_16x16x32_bf16(a, b, c, 0, 0, 0);
}

// async global->LDS, 16B per lane; lds dest is wave-uniform base + lane*16
#define GLDS16(gp, lp)                                                            \
  __builtin_amdgcn_global_load_lds((const __attribute__((address_space(1))) void*)(gp), \
                                   (__attribute__((address_space(3))) void*)(lp), 16, 0, 0)

// ---------------------------------------------------------------------------
// Bias pack: bqkv[1536] = [bq | bk | bv]
// ---------------------------------------------------------------------------
__global__ void pack_bias_k(const float* __restrict__ bq, const float* __restrict__ bk,
                            const float* __restrict__ bv, float* __restrict__ bqkv) {
  int i = blockIdx.x * 256 + threadIdx.x;
  if (i < 512) bqkv[i] = bq[i];
  else if (i < 1024) bqkv[i] = bk[i - 512];
  else if (i < 1536) bqkv[i] = bv[i - 1024];
}

// ---------------------------------------------------------------------------
// Transpose+convert: out[C][R] (bf16) = in[R][C] (f32). Grid (C/32, R/32), block (32,8)
// ---------------------------------------------------------------------------
__global__ void tconv_w(const float* __restrict__ in, u16* __restrict__ out, int R, int C) {
  __shared__ float t[32][33];
  int c0 = blockIdx.x * 32, r0 = blockIdx.y * 32;
  int tx = threadIdx.x, ty = threadIdx.y;
#pragma unroll
  for (int j = 0; j < 4; ++j)
    t[ty * 4 + j][tx] = in[(size_t)(r0 + ty * 4 + j) * C + c0 + tx];
  __syncthreads();
#pragma unroll
  for (int j = 0; j < 4; ++j)
    out[(size_t)(c0 + ty * 4 + j) * R + r0 + tx] = f2bf(t[tx][ty * 4 + j]);
}

// ---------------------------------------------------------------------------
// V transpose (bf16->bf16): per batch z, in = qkv rows [4096] cols[1024..1536) stride 1536
// out = Vt[b][512][4096]. Grid (16,128,4), block (32,8)
// ---------------------------------------------------------------------------
__global__ void tpose_v(const u16* __restrict__ qkv, u16* __restrict__ Vt) {
  __shared__ u16 t[32][41];
  int b = blockIdx.z;
  int c0 = blockIdx.x * 32, r0 = blockIdx.y * 32;
  int tx = threadIdx.x, ty = threadIdx.y;
  const u16* in = qkv + (size_t)b * 4096 * 1536 + 1024;
  u16* outp = Vt + (size_t)b * 512 * 4096;
#pragma unroll
  for (int j = 0; j < 4; ++j)
    t[ty * 4 + j][tx] = in[(size_t)(r0 + ty * 4 + j) * 1536 + c0 + tx];
  __syncthreads();
#pragma unroll
  for (int j = 0; j < 4; ++j)
    outp[(size_t)(c0 + ty * 4 + j) * 4096 + r0 + tx] = t[tx][ty * 4 + j];
}

// ---------------------------------------------------------------------------
// LayerNorm: x f32 [R][512] -> out bf16 [R][512]. 1 wave per row, 4 rows/block.
// ---------------------------------------------------------------------------
__global__ __launch_bounds__(256) void ln_fwd(const float* __restrict__ x,
                                              const float* __restrict__ gw,
                                              const float* __restrict__ bw,
                                              u16* __restrict__ out) {
  int row = blockIdx.x * 4 + (threadIdx.x >> 6);
  int lane = threadIdx.x & 63;
  const float* xr = x + (size_t)row * 512;
  float xv[8], gv[8], bv[8];
  *(float4*)&xv[0] = *(const float4*)(xr + lane * 8);
  *(float4*)&xv[4] = *(const float4*)(xr + lane * 8 + 4);
  *(float4*)&gv[0] = *(const float4*)(gw + lane * 8);
  *(float4*)&gv[4] = *(const float4*)(gw + lane * 8 + 4);
  *(float4*)&bv[0] = *(const float4*)(bw + lane * 8);
  *(float4*)&bv[4] = *(const float4*)(bw + lane * 8 + 4);
  float sum = 0.f, sq = 0.f;
#pragma unroll
  for (int j = 0; j < 8; ++j) { sum += xv[j]; sq += xv[j] * xv[j]; }
#pragma unroll
  for (int d = 1; d < 64; d <<= 1) {
    sum += __shfl_xor(sum, d);
    sq += __shfl_xor(sq, d);
  }
  float mean = sum * (1.f / 512.f);
  float var = sq * (1.f / 512.f) - mean * mean;
  float rstd = rsqrtf(var + 1e-5f);
  union { uint4 u; u16 h[8]; } ob;
#pragma unroll
  for (int j = 0; j < 8; ++j)
    ob.h[j] = f2bf((xv[j] - mean) * rstd * gv[j] + bv[j]);
  *(uint4*)(out + (size_t)row * 512 + lane * 8) = ob.u;
}

// ---------------------------------------------------------------------------
// Row softmax in-place on bf16 scores [rows][4096]; applies scale 1/sqrt(512).
// ---------------------------------------------------------------------------
__global__ __launch_bounds__(256) void softmax_rows(u16* __restrict__ sc) {
  __shared__ float red[8];
  const int tid = threadIdx.x;
  const int lane = tid & 63, w = tid >> 6;
  u16* sr = sc + (size_t)blockIdx.x * 4096 + tid * 16;
  uint4 a = *(const uint4*)sr;
  uint4 b = *(const uint4*)(sr + 8);
  const u16* ap = (const u16*)&a;
  const u16* bp = (const u16*)&b;
  float v[16];
#pragma unroll
  for (int i = 0; i < 8; ++i) {
    v[i] = __uint_as_float((unsigned)ap[i] << 16);
    v[8 + i] = __uint_as_float((unsigned)bp[i] << 16);
  }
  float m = v[0];
#pragma unroll
  for (int i = 1; i < 16; ++i) m = fmaxf(m, v[i]);
#pragma unroll
  for (int d = 1; d < 64; d <<= 1) m = fmaxf(m, __shfl_xor(m, d));
  if (lane == 0) red[w] = m;
  __syncthreads();
  m = fmaxf(fmaxf(red[0], red[1]), fmaxf(red[2], red[3]));
  const float scale = 0.044194173824159216f;  // 512^-0.5
  float s = 0.f;
#pragma unroll
  for (int i = 0; i < 16; ++i) {
    v[i] = __expf((v[i] - m) * scale);
    s += v[i];
  }
#pragma unroll
  for (int d = 1; d < 64; d <<= 1) s += __shfl_xor(s, d);
  if (lane == 0) red[4 + w] = s;
  __syncthreads();
  s = (red[4] + red[5]) + (red[6] + red[7]);
  float inv = 1.f / s;
  union { uint4 u; u16 h[8]; } o1, o2;
#pragma unroll
  for (int i = 0; i < 8; ++i) {
    o1.h[i] = f2bf(v[i] * inv);
    o2.h[i] = f2bf(v[8 + i] * inv);
  }
  *(uint4*)sr = o1.u;
  *(uint4*)(sr + 8) = o2.u;
}

// ---------------------------------------------------------------------------
// GEMM: C[M][N] = A[M][K](bf16, row stride lda) * Bt[N][K](bf16, row stride ldb)^T
// Batched over blockIdx.z with element strides sA/sB/sC.
// EPI 0: out bf16 = acc               (scores, PV)
// EPI 1: out bf16 = acc + bias        (QKV)
// EPI 2: out bf16 = gelu(acc + bias)  (MLP1, tanh-form)
// EPI 3: out f32  = acc + bias + res  (Wo-proj, MLP2)
// 128x128 tile, BK=64, 256 threads (4 waves, 2x2), wave does 64x64 (4x4 frags).
// Double-buffered LDS + stage-ahead: ONE __syncthreads per K-tile; tile t+1's
// global_load_lds issues before tile t's compute (T3-minimum pipeline).
// ---------------------------------------------------------------------------
template <int EPI>
__global__ __launch_bounds__(256, 2) void gemm_bt(const u16* __restrict__ A, int lda, size_t sA,
                                                  const u16* __restrict__ Bt, int ldb, size_t sB,
                                                  const float* __restrict__ bias,
                                                  const float* __restrict__ res,
                                                  void* __restrict__ out, int ldc, size_t sC,
                                                  int M, int N, int K) {
  __shared__ u16 As[2][128 * 64];
  __shared__ u16 Bs[2][128 * 64];
  const int tid = threadIdx.x;
  const int lane = tid & 63, w = tid >> 6;
  const int wr = w >> 1, wc = w & 1;
  const int m0 = blockIdx.x * 128, n0 = blockIdx.y * 128;
  const int lh = lane >> 4, ll = lane & 15;
  A += (size_t)blockIdx.z * sA;
  Bt += (size_t)blockIdx.z * sB;

  // wave w stages rows [w*32, w*32+32); each GLDS16 covers 8 rows (64 lanes x 16B)
  const int srow = w * 32 + (lane >> 3);
  const int scol = (lane & 7) * 8;
  const u16* ga = A + (size_t)(m0 + srow) * lda + scol;
  const u16* gb = Bt + (size_t)(n0 + srow) * ldb + scol;

#define STAGE_BT(buf, kt)                                                      \
  do {                                                                         \
    const size_t k0 = (size_t)(kt) << 6;                                       \
    _Pragma("unroll")                                                          \
    for (int j = 0; j < 4; ++j) {                                              \
      GLDS16(ga + (size_t)(j * 8) * lda + k0, &As[buf][(w * 32 + j * 8) * 64]); \
      GLDS16(gb + (size_t)(j * 8) * ldb + k0, &Bs[buf][(w * 32 + j * 8) * 64]); \
    }                                                                          \
  } while (0)

  f32x4 acc[4][4] = {};
  const int nk = K >> 6;

  STAGE_BT(0, 0);
  __syncthreads();
  int cur = 0;
  for (int kt = 0; kt < nk; ++kt) {
    if (kt + 1 < nk) STAGE_BT(cur ^ 1, kt + 1);
#pragma unroll
    for (int ks = 0; ks < 2; ++ks) {
      bf16x8 a[4], b[4];
#pragma unroll
      for (int m = 0; m < 4; ++m)
        a[m] = *(const bf16x8*)&As[cur][(wr * 64 + m * 16 + ll) * 64 + ks * 32 + lh * 8];
#pragma unroll
      for (int n = 0; n < 4; ++n)
        b[n] = *(const bf16x8*)&Bs[cur][(wc * 64 + n * 16 + ll) * 64 + ks * 32 + lh * 8];
#pragma unroll
      for (int m = 0; m < 4; ++m)
#pragma unroll
        for (int n = 0; n < 4; ++n)
          acc[m][n] = mfma16(a[m], b[n], acc[m][n]);
    }
    __syncthreads();  // drains vmcnt (tile kt+1 landed) + lgkm + barrier
    cur ^= 1;
  }
#undef STAGE_BT

  // epilogue (C/D layout: col = lane&15, row = (lane>>4)*4 + i, verified m89)
  u16* outh = (u16*)out + (size_t)blockIdx.z * sC;
  float* outf = (float*)out + (size_t)blockIdx.z * sC;
#pragma unroll
  for (int m = 0; m < 4; ++m) {
    int row = m0 + wr * 64 + m * 16 + lh * 4;
#pragma unroll
    for (int n = 0; n < 4; ++n) {
      int col = n0 + wc * 64 + n * 16 + ll;
      float bv = (EPI == 0) ? 0.f : bias[col];
#pragma unroll
      for (int i = 0; i < 4; ++i) {
        float v = acc[m][n][i] + bv;
        size_t idx = (size_t)(row + i) * ldc + col;
        if (EPI == 2) {
          // tanh-form gelu; max dev from erf-gelu ~3e-4 << bf16 ulp of m1
          float y = 0.7978845608028654f * (v + 0.044715f * v * v * v);
          v = v / (1.f + __expf(-2.f * y));
        }
        if (EPI == 3)
          outf[idx] = v + res[(size_t)blockIdx.z * sC + idx];
        else
          outh[idx] = f2bf(v);
      }
    }
  }
}

// ---------------------------------------------------------------------------
extern "C" void kernel_launch(void* const* d_in, const int* in_sizes, int n_in,
                              void* d_out, int out_size, void* d_ws, size_t ws_size,
                              hipStream_t stream) {
  const float* x     = (const float*)d_in[0];
  const float* ln1g  = (const float*)d_in[1];
  const float* ln1b  = (const float*)d_in[2];
  const float* Wq    = (const float*)d_in[3];
  const float* bq    = (const float*)d_in[4];
  const float* Wk    = (const float*)d_in[5];
  const float* bk    = (const float*)d_in[6];
  const float* Wv    = (const float*)d_in[7];
  const float* bv    = (const float*)d_in[8];
  const float* Wo    = (const float*)d_in[9];
  const float* bo    = (const float*)d_in[10];
  const float* ln2g  = (const float*)d_in[11];
  const float* ln2b  = (const float*)d_in[12];
  const float* W1    = (const float*)d_in[13];
  const float* b1    = (const float*)d_in[14];
  const float* W2    = (const float*)d_in[15];
  const float* b2    = (const float*)d_in[16];

  char* base = (char*)d_ws;
  u16* Wqkvt = (u16*)base;                      // [1536][512]
  u16* Wot   = Wqkvt + 786432;                  // [512][512]
  u16* W1t   = Wot + 262144;                    // [2048][512]
  u16* W2t   = W1t + 1048576;                   // [512][2048]
  float* bqkv = (float*)(W2t + 1048576);        // [1536]
  u16* qkvb = (u16*)(base + (8ull << 20));      // [16384][1536] bf16
  u16* Vt   = qkvb + (size_t)16384 * 1536;      // [4][512][4096] bf16
  u16* m1   = qkvb;                             // alias (qkv+Vt dead by MLP)
  u16* hb   = (u16*)(base + (72ull << 20));     // h/o/h2 [16384][512] bf16
  const size_t sco_off = 88ull << 20;
  u16* scores = (u16*)(base + sco_off);         // [nb][4096][4096] bf16
  float* x1 = (float*)scores;                   // alias (scores dead by Wo)

  const size_t S = 4096;
  const size_t per_b = S * S * 2;
  int nb = 1;
  if (ws_size >= sco_off + 4 * per_b) nb = 4;
  else if (ws_size >= sco_off + 2 * per_b) nb = 2;

  dim3 tb(32, 8);
  pack_bias_k<<<6, 256, 0, stream>>>(bq, bk, bv, bqkv);
  tconv_w<<<dim3(16, 16), tb, 0, stream>>>(Wq, Wqkvt, 512, 512);
  tconv_w<<<dim3(16, 16), tb, 0, stream>>>(Wk, Wqkvt + 262144, 512, 512);
  tconv_w<<<dim3(16, 16), tb, 0, stream>>>(Wv, Wqkvt + 524288, 512, 512);
  tconv_w<<<dim3(16, 16), tb, 0, stream>>>(Wo, Wot, 512, 512);
  tconv_w<<<dim3(64, 16), tb, 0, stream>>>(W1, W1t, 512, 2048);
  tconv_w<<<dim3(16, 64), tb, 0, stream>>>(W2, W2t, 2048, 512);

  // h = LN1(x)
  ln_fwd<<<4096, 256, 0, stream>>>(x, ln1g, ln1b, hb);
  // qkv = h @ Wqkv + b
  gemm_bt<1><<<dim3(128, 12, 1), 256, 0, stream>>>(hb, 512, 0, Wqkvt, 512, 0, bqkv, nullptr,
                                                   qkvb, 1536, 0, 16384, 1536, 512);
  // Vt = transpose(v)
  tpose_v<<<dim3(16, 128, 4), tb, 0, stream>>>(qkvb, Vt);

  // attention, nb batches per chunk
  for (int b0 = 0; b0 < 4; b0 += nb) {
    int nz = (4 - b0) < nb ? (4 - b0) : nb;
    const u16* qk = qkvb + (size_t)b0 * S * 1536;
    // scores[z] = Q @ K^T (bf16, unscaled)
    gemm_bt<0><<<dim3(32, 32, nz), 256, 0, stream>>>(qk, 1536, S * 1536, qk + 512, 1536, S * 1536,
                                                     nullptr, nullptr, scores, 4096, S * S,
                                                     4096, 4096, 512);
    // P = softmax(scores * scale), in place
    softmax_rows<<<nz * 4096, 256, 0, stream>>>(scores);
    // O[z] = P @ V
    gemm_bt<0><<<dim3(32, 4, nz), 256, 0, stream>>>(scores, 4096, S * S,
                                                    Vt + (size_t)b0 * 512 * S, 4096, 512 * S,
                                                    nullptr, nullptr,
                                                    hb + (size_t)b0 * S * 512, 512, S * 512,
                                                    4096, 512, 4096);
  }

  // x1 = x + o @ Wo + bo
  gemm_bt<3><<<dim3(128, 4, 1), 256, 0, stream>>>(hb, 512, 0, Wot, 512, 0, bo, x,
                                                  x1, 512, 0, 16384, 512, 512);
  // h2 = LN2(x1)
  ln_fwd<<<4096, 256, 0, stream>>>(x1, ln2g, ln2b, hb);
  // m1 = gelu(h2 @ W1 + b1)
  gemm_bt<2><<<dim3(128, 16, 1), 256, 0, stream>>>(hb, 512, 0, W1t, 512, 0, b1, nullptr,
                                                   m1, 2048, 0, 16384, 2048, 512);
  // out = x1 + m1 @ W2 + b2
  gemm_bt<3><<<dim3(128, 4, 1), 256, 0, stream>>>(m1, 2048, 0, W2t, 2048, 0, b2, x1,
                                                  (float*)d_out, 512, 0, 16384, 512, 2048);
}

// Round 7
// 404.134 us; speedup vs baseline: 1.1781x; 1.1781x over previous
//
#include <hip/hip_runtime.h>

typedef unsigned short u16;
typedef float f32x4 __attribute__((ext_vector_type(4)));
typedef __bf16 bf16x8 __attribute__((ext_vector_type(8)));

__device__ __forceinline__ u16 f2bf(float f) {
  unsigned u = __float_as_uint(f);
  u += 0x7fffu + ((u >> 16) & 1u);
  return (u16)(u >> 16);
}

__device__ __forceinline__ f32x4 mfma16(bf16x8 a, bf16x8 b, f32x4 c) {
  return __builtin_amdgcn_mfma_f32_16x16x32_bf16(a, b, c, 0, 0, 0);
}

// async global->LDS, 16B per lane; lds dest is wave-uniform base + lane*16
#define GLDS16(gp, lp)                                                            \
  __builtin_amdgcn_global_load_lds((const __attribute__((address_space(1))) void*)(gp), \
                                   (__attribute__((address_space(3))) void*)(lp), 16, 0, 0)

// ---------------------------------------------------------------------------
// Bias pack: bqkv[1536] = [bq | bk | bv]
// ---------------------------------------------------------------------------
__global__ void pack_bias_k(const float* __restrict__ bq, const float* __restrict__ bk,
                            const float* __restrict__ bv, float* __restrict__ bqkv) {
  int i = blockIdx.x * 256 + threadIdx.x;
  if (i < 512) bqkv[i] = bq[i];
  else if (i < 1024) bqkv[i] = bk[i - 512];
  else if (i < 1536) bqkv[i] = bv[i - 1024];
}

// ---------------------------------------------------------------------------
// Transpose+convert: out[C][R] (bf16) = in[R][C] (f32). Grid (C/32, R/32), block (32,8)
// ---------------------------------------------------------------------------
__global__ void tconv_w(const float* __restrict__ in, u16* __restrict__ out, int R, int C) {
  __shared__ float t[32][33];
  int c0 = blockIdx.x * 32, r0 = blockIdx.y * 32;
  int tx = threadIdx.x, ty = threadIdx.y;
#pragma unroll
  for (int j = 0; j < 4; ++j)
    t[ty * 4 + j][tx] = in[(size_t)(r0 + ty * 4 + j) * C + c0 + tx];
  __syncthreads();
#pragma unroll
  for (int j = 0; j < 4; ++j)
    out[(size_t)(c0 + ty * 4 + j) * R + r0 + tx] = f2bf(t[tx][ty * 4 + j]);
}

// ---------------------------------------------------------------------------
// V transpose (bf16->bf16): per batch z, in = qkv rows [4096] cols[1024..1536) stride 1536
// out = Vt[b][512][4096]. Grid (16,128,4), block (32,8)
// ---------------------------------------------------------------------------
__global__ void tpose_v(const u16* __restrict__ qkv, u16* __restrict__ Vt) {
  __shared__ u16 t[32][41];
  int b = blockIdx.z;
  int c0 = blockIdx.x * 32, r0 = blockIdx.y * 32;
  int tx = threadIdx.x, ty = threadIdx.y;
  const u16* in = qkv + (size_t)b * 4096 * 1536 + 1024;
  u16* outp = Vt + (size_t)b * 512 * 4096;
#pragma unroll
  for (int j = 0; j < 4; ++j)
    t[ty * 4 + j][tx] = in[(size_t)(r0 + ty * 4 + j) * 1536 + c0 + tx];
  __syncthreads();
#pragma unroll
  for (int j = 0; j < 4; ++j)
    outp[(size_t)(c0 + ty * 4 + j) * 4096 + r0 + tx] = t[tx][ty * 4 + j];
}

// ---------------------------------------------------------------------------
// LayerNorm: x f32 [R][512] -> out bf16 [R][512]. 1 wave per row, 4 rows/block.
// ---------------------------------------------------------------------------
__global__ __launch_bounds__(256) void ln_fwd(const float* __restrict__ x,
                                              const float* __restrict__ gw,
                                              const float* __restrict__ bw,
                                              u16* __restrict__ out) {
  int row = blockIdx.x * 4 + (threadIdx.x >> 6);
  int lane = threadIdx.x & 63;
  const float* xr = x + (size_t)row * 512;
  float xv[8], gv[8], bv[8];
  *(float4*)&xv[0] = *(const float4*)(xr + lane * 8);
  *(float4*)&xv[4] = *(const float4*)(xr + lane * 8 + 4);
  *(float4*)&gv[0] = *(const float4*)(gw + lane * 8);
  *(float4*)&gv[4] = *(const float4*)(gw + lane * 8 + 4);
  *(float4*)&bv[0] = *(const float4*)(bw + lane * 8);
  *(float4*)&bv[4] = *(const float4*)(bw + lane * 8 + 4);
  float sum = 0.f, sq = 0.f;
#pragma unroll
  for (int j = 0; j < 8; ++j) { sum += xv[j]; sq += xv[j] * xv[j]; }
#pragma unroll
  for (int d = 1; d < 64; d <<= 1) {
    sum += __shfl_xor(sum, d);
    sq += __shfl_xor(sq, d);
  }
  float mean = sum * (1.f / 512.f);
  float var = sq * (1.f / 512.f) - mean * mean;
  float rstd = rsqrtf(var + 1e-5f);
  union { uint4 u; u16 h[8]; } ob;
#pragma unroll
  for (int j = 0; j < 8; ++j)
    ob.h[j] = f2bf((xv[j] - mean) * rstd * gv[j] + bv[j]);
  *(uint4*)(out + (size_t)row * 512 + lane * 8) = ob.u;
}

// ---------------------------------------------------------------------------
// GEMM: C[M][N] = A[M][K](bf16, row stride lda) * Bt[N][K](bf16, row stride ldb)^T
// Batched over blockIdx.z with element strides sA/sB/sC.
// EPI 0: out bf16 = acc
// EPI 1: out bf16 = acc + bias          (QKV)
// EPI 2: out bf16 = gelu(acc + bias)    (MLP1, tanh-form)
// EPI 3: out f32  = acc + bias + res    (Wo-proj, MLP2)
// EPI 4: out bf16 = acc / rowsum(A)     (PV; rowsum via ones-B MFMA)
// EPI 5: out bf16 = exp(acc * 1/sqrt(512))  (QK -> unnormalized softmax)
// 128x128 tile, BK=64, 256 threads (4 waves, 2x2), wave does 64x64 (4x4 frags).
// Staging: global_load_lds dwordx4, linear [128][64] LDS tiles (round-4-proven).
// ---------------------------------------------------------------------------
template <int EPI>
__global__ __launch_bounds__(256, 2) void gemm_bt(const u16* __restrict__ A, int lda, size_t sA,
                                                  const u16* __restrict__ Bt, int ldb, size_t sB,
                                                  const float* __restrict__ bias,
                                                  const float* __restrict__ res,
                                                  void* __restrict__ out, int ldc, size_t sC,
                                                  int M, int N, int K) {
  __shared__ u16 As[128 * 64];
  __shared__ u16 Bs[128 * 64];
  const int tid = threadIdx.x;
  const int lane = tid & 63, w = tid >> 6;
  const int wr = w >> 1, wc = w & 1;
  const int m0 = blockIdx.x * 128, n0 = blockIdx.y * 128;
  const int lh = lane >> 4, ll = lane & 15;
  A += (size_t)blockIdx.z * sA;
  Bt += (size_t)blockIdx.z * sB;

  // wave w stages rows [w*32, w*32+32); each GLDS16 covers 8 rows (64 lanes x 16B)
  const int srow = w * 32 + (lane >> 3);
  const int scol = (lane & 7) * 8;
  const u16* ga = A + (size_t)(m0 + srow) * lda + scol;
  const u16* gb = Bt + (size_t)(n0 + srow) * ldb + scol;

  // all-ones B fragment for inline row-sum (EPI 4)
  bf16x8 ones;
#pragma unroll
  for (int j = 0; j < 8; ++j) ones[j] = (__bf16)1.0f;

  f32x4 acc[4][4] = {};
  f32x4 accs[4] = {};
  const int nk = K >> 6;
  for (int kt = 0; kt < nk; ++kt) {
    const int k0 = kt << 6;
#pragma unroll
    for (int j = 0; j < 4; ++j) {
      GLDS16(ga + (size_t)(j * 8) * lda + k0, &As[(w * 32 + j * 8) * 64]);
      GLDS16(gb + (size_t)(j * 8) * ldb + k0, &Bs[(w * 32 + j * 8) * 64]);
    }
    __syncthreads();
#pragma unroll
    for (int ks = 0; ks < 2; ++ks) {
      bf16x8 a[4], b[4];
#pragma unroll
      for (int m = 0; m < 4; ++m)
        a[m] = *(const bf16x8*)&As[(wr * 64 + m * 16 + ll) * 64 + ks * 32 + lh * 8];
#pragma unroll
      for (int n = 0; n < 4; ++n)
        b[n] = *(const bf16x8*)&Bs[(wc * 64 + n * 16 + ll) * 64 + ks * 32 + lh * 8];
#pragma unroll
      for (int m = 0; m < 4; ++m)
#pragma unroll
        for (int n = 0; n < 4; ++n)
          acc[m][n] = mfma16(a[m], b[n], acc[m][n]);
      if (EPI == 4) {
#pragma unroll
        for (int m = 0; m < 4; ++m) accs[m] = mfma16(a[m], ones, accs[m]);
      }
    }
    __syncthreads();
  }

  // epilogue (C/D layout: col = lane&15, row = (lane>>4)*4 + i, verified m89)
  u16* outh = (u16*)out + (size_t)blockIdx.z * sC;
  float* outf = (float*)out + (size_t)blockIdx.z * sC;
#pragma unroll
  for (int m = 0; m < 4; ++m) {
    int row = m0 + wr * 64 + m * 16 + lh * 4;
#pragma unroll
    for (int n = 0; n < 4; ++n) {
      int col = n0 + wc * 64 + n * 16 + ll;
      float bv = (EPI == 1 || EPI == 2 || EPI == 3) ? bias[col] : 0.f;
#pragma unroll
      for (int i = 0; i < 4; ++i) {
        float v = acc[m][n][i] + bv;
        size_t idx = (size_t)(row + i) * ldc + col;
        if (EPI == 2) {
          // tanh-form gelu; max dev from erf-gelu ~3e-4 << bf16 ulp of m1
          float y = 0.7978845608028654f * (v + 0.044715f * v * v * v);
          v = v / (1.f + __expf(-2.f * y));
        }
        if (EPI == 4) v = v * (1.f / accs[m][i]);   // rowsum > 0 always
        if (EPI == 5) v = __expf(v * 0.044194173824159216f);  // 512^-0.5
        if (EPI == 3)
          outf[idx] = v + res[(size_t)blockIdx.z * sC + idx];
        else
          outh[idx] = f2bf(v);
      }
    }
  }
}

// ---------------------------------------------------------------------------
extern "C" void kernel_launch(void* const* d_in, const int* in_sizes, int n_in,
                              void* d_out, int out_size, void* d_ws, size_t ws_size,
                              hipStream_t stream) {
  const float* x     = (const float*)d_in[0];
  const float* ln1g  = (const float*)d_in[1];
  const float* ln1b  = (const float*)d_in[2];
  const float* Wq    = (const float*)d_in[3];
  const float* bq    = (const float*)d_in[4];
  const float* Wk    = (const float*)d_in[5];
  const float* bk    = (const float*)d_in[6];
  const float* Wv    = (const float*)d_in[7];
  const float* bv    = (const float*)d_in[8];
  const float* Wo    = (const float*)d_in[9];
  const float* bo    = (const float*)d_in[10];
  const float* ln2g  = (const float*)d_in[11];
  const float* ln2b  = (const float*)d_in[12];
  const float* W1    = (const float*)d_in[13];
  const float* b1    = (const float*)d_in[14];
  const float* W2    = (const float*)d_in[15];
  const float* b2    = (const float*)d_in[16];

  char* base = (char*)d_ws;
  u16* Wqkvt = (u16*)base;                      // [1536][512]
  u16* Wot   = Wqkvt + 786432;                  // [512][512]
  u16* W1t   = Wot + 262144;                    // [2048][512]
  u16* W2t   = W1t + 1048576;                   // [512][2048]
  float* bqkv = (float*)(W2t + 1048576);        // [1536]
  u16* qkvb = (u16*)(base + (8ull << 20));      // [16384][1536] bf16
  u16* Vt   = qkvb + (size_t)16384 * 1536;      // [4][512][4096] bf16
  u16* m1   = qkvb;                             // alias (qkv+Vt dead by MLP)
  u16* hb   = (u16*)(base + (72ull << 20));     // h/o/h2 [16384][512] bf16
  const size_t sco_off = 88ull << 20;
  u16* scores = (u16*)(base + sco_off);         // [nb][4096][4096] bf16 (exp-scores)
  float* x1 = (float*)scores;                   // alias (scores dead by Wo)

  const size_t S = 4096;
  const size_t per_b = S * S * 2;
  int nb = 1;
  if (ws_size >= sco_off + 4 * per_b) nb = 4;
  else if (ws_size >= sco_off + 2 * per_b) nb = 2;

  dim3 tb(32, 8);
  pack_bias_k<<<6, 256, 0, stream>>>(bq, bk, bv, bqkv);
  tconv_w<<<dim3(16, 16), tb, 0, stream>>>(Wq, Wqkvt, 512, 512);
  tconv_w<<<dim3(16, 16), tb, 0, stream>>>(Wk, Wqkvt + 262144, 512, 512);
  tconv_w<<<dim3(16, 16), tb, 0, stream>>>(Wv, Wqkvt + 524288, 512, 512);
  tconv_w<<<dim3(16, 16), tb, 0, stream>>>(Wo, Wot, 512, 512);
  tconv_w<<<dim3(64, 16), tb, 0, stream>>>(W1, W1t, 512, 2048);
  tconv_w<<<dim3(16, 64), tb, 0, stream>>>(W2, W2t, 2048, 512);

  // h = LN1(x)
  ln_fwd<<<4096, 256, 0, stream>>>(x, ln1g, ln1b, hb);
  // qkv = h @ Wqkv + b
  gemm_bt<1><<<dim3(128, 12, 1), 256, 0, stream>>>(hb, 512, 0, Wqkvt, 512, 0, bqkv, nullptr,
                                                   qkvb, 1536, 0, 16384, 1536, 512);
  // Vt = transpose(v)
  tpose_v<<<dim3(16, 128, 4), tb, 0, stream>>>(qkvb, Vt);

  // attention, nb batches per chunk; softmax fused: QK writes exp(s*scale),
  // PV normalizes by inline row-sum.
  for (int b0 = 0; b0 < 4; b0 += nb) {
    int nz = (4 - b0) < nb ? (4 - b0) : nb;
    const u16* qk = qkvb + (size_t)b0 * S * 1536;
    // scores[z] = exp(Q @ K^T * scale)   (bf16, unnormalized)
    gemm_bt<5><<<dim3(32, 32, nz), 256, 0, stream>>>(qk, 1536, S * 1536, qk + 512, 1536, S * 1536,
                                                     nullptr, nullptr, scores, 4096, S * S,
                                                     4096, 4096, 512);
    // O[z] = (P~ @ V) / rowsum(P~)
    gemm_bt<4><<<dim3(32, 4, nz), 256, 0, stream>>>(scores, 4096, S * S,
                                                    Vt + (size_t)b0 * 512 * S, 4096, 512 * S,
                                                    nullptr, nullptr,
                                                    hb + (size_t)b0 * S * 512, 512, S * 512,
                                                    4096, 512, 4096);
  }

  // x1 = x + o @ Wo + bo
  gemm_bt<3><<<dim3(128, 4, 1), 256, 0, stream>>>(hb, 512, 0, Wot, 512, 0, bo, x,
                                                  x1, 512, 0, 16384, 512, 512);
  // h2 = LN2(x1)
  ln_fwd<<<4096, 256, 0, stream>>>(x1, ln2g, ln2b, hb);
  // m1 = gelu(h2 @ W1 + b1)
  gemm_bt<2><<<dim3(128, 16, 1), 256, 0, stream>>>(hb, 512, 0, W1t, 512, 0, b1, nullptr,
                                                   m1, 2048, 0, 16384, 2048, 512);
  // out = x1 + m1 @ W2 + b2
  gemm_bt<3><<<dim3(128, 4, 1), 256, 0, stream>>>(m1, 2048, 0, W2t, 2048, 0, b2, x1,
                                                  (float*)d_out, 512, 0, 16384, 512, 2048);
}

// Round 8
// 375.424 us; speedup vs baseline: 1.2682x; 1.0765x over previous
//
#include <hip/hip_runtime.h>

typedef unsigned short u16;
typedef float f32x4 __attribute__((ext_vector_type(4)));
typedef __bf16 bf16x8 __attribute__((ext_vector_type(8)));

__device__ __forceinline__ u16 f2bf(float f) {
  unsigned u = __float_as_uint(f);
  u += 0x7fffu + ((u >> 16) & 1u);
  return (u16)(u >> 16);
}

__device__ __forceinline__ f32x4 mfma16(bf16x8 a, bf16x8 b, f32x4 c) {
  return __builtin_amdgcn_mfma_f32_16x16x32_bf16(a, b, c, 0, 0, 0);
}

// async global->LDS, 16B per lane; lds dest is wave-uniform base + lane*16
#define GLDS16(gp, lp)                                                            \
  __builtin_amdgcn_global_load_lds((const __attribute__((address_space(1))) void*)(gp), \
                                   (__attribute__((address_space(3))) void*)(lp), 16, 0, 0)

// ---------------------------------------------------------------------------
// Bias pack: bqkv[1536] = [bq | bk | bv]
// ---------------------------------------------------------------------------
__global__ void pack_bias_k(const float* __restrict__ bq, const float* __restrict__ bk,
                            const float* __restrict__ bv, float* __restrict__ bqkv) {
  int i = blockIdx.x * 256 + threadIdx.x;
  if (i < 512) bqkv[i] = bq[i];
  else if (i < 1024) bqkv[i] = bk[i - 512];
  else if (i < 1536) bqkv[i] = bv[i - 1024];
}

// ---------------------------------------------------------------------------
// Transpose+convert: out[C][R] (bf16) = in[R][C] (f32). Grid (C/32, R/32), block (32,8)
// ---------------------------------------------------------------------------
__global__ void tconv_w(const float* __restrict__ in, u16* __restrict__ out, int R, int C) {
  __shared__ float t[32][33];
  int c0 = blockIdx.x * 32, r0 = blockIdx.y * 32;
  int tx = threadIdx.x, ty = threadIdx.y;
#pragma unroll
  for (int j = 0; j < 4; ++j)
    t[ty * 4 + j][tx] = in[(size_t)(r0 + ty * 4 + j) * C + c0 + tx];
  __syncthreads();
#pragma unroll
  for (int j = 0; j < 4; ++j)
    out[(size_t)(c0 + ty * 4 + j) * R + r0 + tx] = f2bf(t[tx][ty * 4 + j]);
}

// ---------------------------------------------------------------------------
// V transpose (bf16->bf16): per batch z, in = qkv rows [4096] cols[1024..1536) stride 1536
// out = Vt[b][512][4096]. Grid (16,128,4), block (32,8)
// ---------------------------------------------------------------------------
__global__ void tpose_v(const u16* __restrict__ qkv, u16* __restrict__ Vt) {
  __shared__ u16 t[32][41];
  int b = blockIdx.z;
  int c0 = blockIdx.x * 32, r0 = blockIdx.y * 32;
  int tx = threadIdx.x, ty = threadIdx.y;
  const u16* in = qkv + (size_t)b * 4096 * 1536 + 1024;
  u16* outp = Vt + (size_t)b * 512 * 4096;
#pragma unroll
  for (int j = 0; j < 4; ++j)
    t[ty * 4 + j][tx] = in[(size_t)(r0 + ty * 4 + j) * 1536 + c0 + tx];
  __syncthreads();
#pragma unroll
  for (int j = 0; j < 4; ++j)
    outp[(size_t)(c0 + ty * 4 + j) * 4096 + r0 + tx] = t[tx][ty * 4 + j];
}

// ---------------------------------------------------------------------------
// LayerNorm: x f32 [R][512] -> out bf16 [R][512]. 1 wave per row, 4 rows/block.
// ---------------------------------------------------------------------------
__global__ __launch_bounds__(256) void ln_fwd(const float* __restrict__ x,
                                              const float* __restrict__ gw,
                                              const float* __restrict__ bw,
                                              u16* __restrict__ out) {
  int row = blockIdx.x * 4 + (threadIdx.x >> 6);
  int lane = threadIdx.x & 63;
  const float* xr = x + (size_t)row * 512;
  float xv[8], gv[8], bv[8];
  *(float4*)&xv[0] = *(const float4*)(xr + lane * 8);
  *(float4*)&xv[4] = *(const float4*)(xr + lane * 8 + 4);
  *(float4*)&gv[0] = *(const float4*)(gw + lane * 8);
  *(float4*)&gv[4] = *(const float4*)(gw + lane * 8 + 4);
  *(float4*)&bv[0] = *(const float4*)(bw + lane * 8);
  *(float4*)&bv[4] = *(const float4*)(bw + lane * 8 + 4);
  float sum = 0.f, sq = 0.f;
#pragma unroll
  for (int j = 0; j < 8; ++j) { sum += xv[j]; sq += xv[j] * xv[j]; }
#pragma unroll
  for (int d = 1; d < 64; d <<= 1) {
    sum += __shfl_xor(sum, d);
    sq += __shfl_xor(sq, d);
  }
  float mean = sum * (1.f / 512.f);
  float var = sq * (1.f / 512.f) - mean * mean;
  float rstd = rsqrtf(var + 1e-5f);
  union { uint4 u; u16 h[8]; } ob;
#pragma unroll
  for (int j = 0; j < 8; ++j)
    ob.h[j] = f2bf((xv[j] - mean) * rstd * gv[j] + bv[j]);
  *(uint4*)(out + (size_t)row * 512 + lane * 8) = ob.u;
}

// ---------------------------------------------------------------------------
// GEMM: C[M][N] = A[M][K](bf16, row stride lda) * Bt[N][K](bf16, row stride ldb)^T
// Batched over blockIdx.z with element strides sA/sB/sC.
// EPI 0: out bf16 = acc
// EPI 1: out bf16 = acc + bias          (QKV)
// EPI 2: out bf16 = gelu(acc + bias)    (MLP1, tanh-form)
// EPI 3: out f32  = acc + bias + res    (Wo-proj, MLP2)
// EPI 4: out bf16 = acc / rowsum(A)     (PV; rowsum via ones-B MFMA)
// EPI 5: out bf16 = exp(acc * 1/sqrt(512))  (QK -> unnormalized softmax)
// 128x128 tile, BK=64, 256 threads (4 waves, 2x2), wave does 64x64 (4x4 frags).
// LDS layout: K-panel split [panel=k/32][128 rows][32 elems] (64-byte rows) so
// fragment reads hit 8 distinct bank-quads (2 lanes/bank = conflict-free).
// Staging keeps linear global_load_lds dest; only per-lane global src remaps.
//   As[p*4096 + r*32 + c] = A[m0+r][k0 + p*32 + c]
// ---------------------------------------------------------------------------
template <int EPI>
__global__ __launch_bounds__(256, 2) void gemm_bt(const u16* __restrict__ A, int lda, size_t sA,
                                                  const u16* __restrict__ Bt, int ldb, size_t sB,
                                                  const float* __restrict__ bias,
                                                  const float* __restrict__ res,
                                                  void* __restrict__ out, int ldc, size_t sC,
                                                  int M, int N, int K) {
  __shared__ u16 As[128 * 64];
  __shared__ u16 Bs[128 * 64];
  const int tid = threadIdx.x;
  const int lane = tid & 63, w = tid >> 6;
  const int wr = w >> 1, wc = w & 1;
  const int m0 = blockIdx.x * 128, n0 = blockIdx.y * 128;
  const int lh = lane >> 4, ll = lane & 15;
  A += (size_t)blockIdx.z * sA;
  Bt += (size_t)blockIdx.z * sB;

  // staging: block t = w*4+j covers panel (t>>3), rows (t&7)*16 + (lane>>2),
  // elems (t>>3)*32 + (lane&3)*8; dest = linear 1024B at As/Bs + t*512
  const int srow = lane >> 2;          // 0..15
  const int scol = (lane & 3) * 8;     // 0,8,16,24
  const u16* ga = A + (size_t)(m0 + srow) * lda + scol;
  const u16* gb = Bt + (size_t)(n0 + srow) * ldb + scol;

  // all-ones B fragment for inline row-sum (EPI 4)
  bf16x8 ones;
#pragma unroll
  for (int j = 0; j < 8; ++j) ones[j] = (__bf16)1.0f;

  f32x4 acc[4][4] = {};
  f32x4 accs[4] = {};
  const int nk = K >> 6;
  for (int kt = 0; kt < nk; ++kt) {
    const int k0 = kt << 6;
#pragma unroll
    for (int j = 0; j < 4; ++j) {
      const int t = w * 4 + j;
      const int radd = (t & 7) * 16;
      const int kadd = (t >> 3) * 32;
      GLDS16(ga + (size_t)radd * lda + k0 + kadd, &As[t * 512]);
      GLDS16(gb + (size_t)radd * ldb + k0 + kadd, &Bs[t * 512]);
    }
    __syncthreads();
#pragma unroll
    for (int ks = 0; ks < 2; ++ks) {
      bf16x8 a[4], b[4];
#pragma unroll
      for (int m = 0; m < 4; ++m)
        a[m] = *(const bf16x8*)&As[ks * 4096 + (wr * 64 + m * 16 + ll) * 32 + lh * 8];
#pragma unroll
      for (int n = 0; n < 4; ++n)
        b[n] = *(const bf16x8*)&Bs[ks * 4096 + (wc * 64 + n * 16 + ll) * 32 + lh * 8];
#pragma unroll
      for (int m = 0; m < 4; ++m)
#pragma unroll
        for (int n = 0; n < 4; ++n)
          acc[m][n] = mfma16(a[m], b[n], acc[m][n]);
      if (EPI == 4) {
#pragma unroll
        for (int m = 0; m < 4; ++m) accs[m] = mfma16(a[m], ones, accs[m]);
      }
    }
    __syncthreads();
  }

  // epilogue (C/D layout: col = lane&15, row = (lane>>4)*4 + i, verified m89)
  u16* outh = (u16*)out + (size_t)blockIdx.z * sC;
  float* outf = (float*)out + (size_t)blockIdx.z * sC;
#pragma unroll
  for (int m = 0; m < 4; ++m) {
    int row = m0 + wr * 64 + m * 16 + lh * 4;
#pragma unroll
    for (int n = 0; n < 4; ++n) {
      int col = n0 + wc * 64 + n * 16 + ll;
      float bv = (EPI == 1 || EPI == 2 || EPI == 3) ? bias[col] : 0.f;
#pragma unroll
      for (int i = 0; i < 4; ++i) {
        float v = acc[m][n][i] + bv;
        size_t idx = (size_t)(row + i) * ldc + col;
        if (EPI == 2) {
          // tanh-form gelu; max dev from erf-gelu ~3e-4 << bf16 ulp of m1
          float y = 0.7978845608028654f * (v + 0.044715f * v * v * v);
          v = v / (1.f + __expf(-2.f * y));
        }
        if (EPI == 4) v = v * (1.f / accs[m][i]);   // rowsum > 0 always
        if (EPI == 5) v = __expf(v * 0.044194173824159216f);  // 512^-0.5
        if (EPI == 3)
          outf[idx] = v + res[(size_t)blockIdx.z * sC + idx];
        else
          outh[idx] = f2bf(v);
      }
    }
  }
}

// ---------------------------------------------------------------------------
extern "C" void kernel_launch(void* const* d_in, const int* in_sizes, int n_in,
                              void* d_out, int out_size, void* d_ws, size_t ws_size,
                              hipStream_t stream) {
  const float* x     = (const float*)d_in[0];
  const float* ln1g  = (const float*)d_in[1];
  const float* ln1b  = (const float*)d_in[2];
  const float* Wq    = (const float*)d_in[3];
  const float* bq    = (const float*)d_in[4];
  const float* Wk    = (const float*)d_in[5];
  const float* bk    = (const float*)d_in[6];
  const float* Wv    = (const float*)d_in[7];
  const float* bv    = (const float*)d_in[8];
  const float* Wo    = (const float*)d_in[9];
  const float* bo    = (const float*)d_in[10];
  const float* ln2g  = (const float*)d_in[11];
  const float* ln2b  = (const float*)d_in[12];
  const float* W1    = (const float*)d_in[13];
  const float* b1    = (const float*)d_in[14];
  const float* W2    = (const float*)d_in[15];
  const float* b2    = (const float*)d_in[16];

  char* base = (char*)d_ws;
  u16* Wqkvt = (u16*)base;                      // [1536][512]
  u16* Wot   = Wqkvt + 786432;                  // [512][512]
  u16* W1t   = Wot + 262144;                    // [2048][512]
  u16* W2t   = W1t + 1048576;                   // [512][2048]
  float* bqkv = (float*)(W2t + 1048576);        // [1536]
  u16* qkvb = (u16*)(base + (8ull << 20));      // [16384][1536] bf16
  u16* Vt   = qkvb + (size_t)16384 * 1536;      // [4][512][4096] bf16
  u16* m1   = qkvb;                             // alias (qkv+Vt dead by MLP)
  u16* hb   = (u16*)(base + (72ull << 20));     // h/o/h2 [16384][512] bf16
  const size_t sco_off = 88ull << 20;
  u16* scores = (u16*)(base + sco_off);         // [nb][4096][4096] bf16 (exp-scores)
  float* x1 = (float*)scores;                   // alias (scores dead by Wo)

  const size_t S = 4096;
  const size_t per_b = S * S * 2;
  int nb = 1;
  if (ws_size >= sco_off + 4 * per_b) nb = 4;
  else if (ws_size >= sco_off + 2 * per_b) nb = 2;

  dim3 tb(32, 8);
  pack_bias_k<<<6, 256, 0, stream>>>(bq, bk, bv, bqkv);
  tconv_w<<<dim3(16, 16), tb, 0, stream>>>(Wq, Wqkvt, 512, 512);
  tconv_w<<<dim3(16, 16), tb, 0, stream>>>(Wk, Wqkvt + 262144, 512, 512);
  tconv_w<<<dim3(16, 16), tb, 0, stream>>>(Wv, Wqkvt + 524288, 512, 512);
  tconv_w<<<dim3(16, 16), tb, 0, stream>>>(Wo, Wot, 512, 512);
  tconv_w<<<dim3(64, 16), tb, 0, stream>>>(W1, W1t, 512, 2048);
  tconv_w<<<dim3(16, 64), tb, 0, stream>>>(W2, W2t, 2048, 512);

  // h = LN1(x)
  ln_fwd<<<4096, 256, 0, stream>>>(x, ln1g, ln1b, hb);
  // qkv = h @ Wqkv + b
  gemm_bt<1><<<dim3(128, 12, 1), 256, 0, stream>>>(hb, 512, 0, Wqkvt, 512, 0, bqkv, nullptr,
                                                   qkvb, 1536, 0, 16384, 1536, 512);
  // Vt = transpose(v)
  tpose_v<<<dim3(16, 128, 4), tb, 0, stream>>>(qkvb, Vt);

  // attention, nb batches per chunk; softmax fused: QK writes exp(s*scale),
  // PV normalizes by inline row-sum.
  for (int b0 = 0; b0 < 4; b0 += nb) {
    int nz = (4 - b0) < nb ? (4 - b0) : nb;
    const u16* qk = qkvb + (size_t)b0 * S * 1536;
    // scores[z] = exp(Q @ K^T * scale)   (bf16, unnormalized)
    gemm_bt<5><<<dim3(32, 32, nz), 256, 0, stream>>>(qk, 1536, S * 1536, qk + 512, 1536, S * 1536,
                                                     nullptr, nullptr, scores, 4096, S * S,
                                                     4096, 4096, 512);
    // O[z] = (P~ @ V) / rowsum(P~)
    gemm_bt<4><<<dim3(32, 4, nz), 256, 0, stream>>>(scores, 4096, S * S,
                                                    Vt + (size_t)b0 * 512 * S, 4096, 512 * S,
                                                    nullptr, nullptr,
                                                    hb + (size_t)b0 * S * 512, 512, S * 512,
                                                    4096, 512, 4096);
  }

  // x1 = x + o @ Wo + bo
  gemm_bt<3><<<dim3(128, 4, 1), 256, 0, stream>>>(hb, 512, 0, Wot, 512, 0, bo, x,
                                                  x1, 512, 0, 16384, 512, 512);
  // h2 = LN2(x1)
  ln_fwd<<<4096, 256, 0, stream>>>(x1, ln2g, ln2b, hb);
  // m1 = gelu(h2 @ W1 + b1)
  gemm_bt<2><<<dim3(128, 16, 1), 256, 0, stream>>>(hb, 512, 0, W1t, 512, 0, b1, nullptr,
                                                   m1, 2048, 0, 16384, 2048, 512);
  // out = x1 + m1 @ W2 + b2
  gemm_bt<3><<<dim3(128, 4, 1), 256, 0, stream>>>(m1, 2048, 0, W2t, 2048, 0, b2, x1,
                                                  (float*)d_out, 512, 0, 16384, 512, 2048);
}

// Round 9
// 352.927 us; speedup vs baseline: 1.3490x; 1.0637x over previous
//
#include <hip/hip_runtime.h>

typedef unsigned short u16;
typedef float f32x4 __attribute__((ext_vector_type(4)));
typedef __bf16 bf16x8 __attribute__((ext_vector_type(8)));

__device__ __forceinline__ u16 f2bf(float f) {
  unsigned u = __float_as_uint(f);
  u += 0x7fffu + ((u >> 16) & 1u);
  return (u16)(u >> 16);
}

__device__ __forceinline__ f32x4 mfma16(bf16x8 a, bf16x8 b, f32x4 c) {
  return __builtin_amdgcn_mfma_f32_16x16x32_bf16(a, b, c, 0, 0, 0);
}

// async global->LDS, 16B per lane; lds dest is wave-uniform base + lane*16
#define GLDS16(gp, lp)                                                            \
  __builtin_amdgcn_global_load_lds((const __attribute__((address_space(1))) void*)(gp), \
                                   (__attribute__((address_space(3))) void*)(lp), 16, 0, 0)

// ---------------------------------------------------------------------------
// prep_all: all weight transposes (f32 [R][C] -> bf16 [C][R]) in ONE launch.
// blocks 0..255 Wq | 256..511 Wk | 512..767 Wv | 768..1023 Wo |
// 1024..2047 W1 (512x2048) | 2048..3071 W2 (2048x512). 256 threads.
// ---------------------------------------------------------------------------
__global__ __launch_bounds__(256) void prep_all(const float* __restrict__ Wq,
                                                const float* __restrict__ Wk,
                                                const float* __restrict__ Wv,
                                                const float* __restrict__ Wo,
                                                const float* __restrict__ W1,
                                                const float* __restrict__ W2,
                                                u16* __restrict__ Wqkvt, u16* __restrict__ Wot,
                                                u16* __restrict__ W1t, u16* __restrict__ W2t) {
  __shared__ float t[32][33];
  const int bid = blockIdx.x;
  const float* in;
  u16* out;
  int R, C, bx, by;
  if (bid < 256) {
    in = Wq; out = Wqkvt; R = 512; C = 512; bx = bid & 15; by = bid >> 4;
  } else if (bid < 512) {
    in = Wk; out = Wqkvt + 262144; R = 512; C = 512; bx = (bid - 256) & 15; by = (bid - 256) >> 4;
  } else if (bid < 768) {
    in = Wv; out = Wqkvt + 524288; R = 512; C = 512; bx = (bid - 512) & 15; by = (bid - 512) >> 4;
  } else if (bid < 1024) {
    in = Wo; out = Wot; R = 512; C = 512; bx = (bid - 768) & 15; by = (bid - 768) >> 4;
  } else if (bid < 2048) {
    in = W1; out = W1t; R = 512; C = 2048; bx = (bid - 1024) & 63; by = (bid - 1024) >> 6;
  } else {
    in = W2; out = W2t; R = 2048; C = 512; bx = (bid - 2048) & 15; by = (bid - 2048) >> 4;
  }
  const int c0 = bx * 32, r0 = by * 32;
  const int tx = threadIdx.x & 31, ty = threadIdx.x >> 5;
#pragma unroll
  for (int j = 0; j < 4; ++j)
    t[ty * 4 + j][tx] = in[(size_t)(r0 + ty * 4 + j) * C + c0 + tx];
  __syncthreads();
#pragma unroll
  for (int j = 0; j < 4; ++j)
    out[(size_t)(c0 + ty * 4 + j) * R + r0 + tx] = f2bf(t[tx][ty * 4 + j]);
}

// ---------------------------------------------------------------------------
// LayerNorm: x f32 [R][512] -> out bf16 [R][512]. 1 wave per row, 4 rows/block.
// ---------------------------------------------------------------------------
__global__ __launch_bounds__(256) void ln_fwd(const float* __restrict__ x,
                                              const float* __restrict__ gw,
                                              const float* __restrict__ bw,
                                              u16* __restrict__ out) {
  int row = blockIdx.x * 4 + (threadIdx.x >> 6);
  int lane = threadIdx.x & 63;
  const float* xr = x + (size_t)row * 512;
  float xv[8], gv[8], bv[8];
  *(float4*)&xv[0] = *(const float4*)(xr + lane * 8);
  *(float4*)&xv[4] = *(const float4*)(xr + lane * 8 + 4);
  *(float4*)&gv[0] = *(const float4*)(gw + lane * 8);
  *(float4*)&gv[4] = *(const float4*)(gw + lane * 8 + 4);
  *(float4*)&bv[0] = *(const float4*)(bw + lane * 8);
  *(float4*)&bv[4] = *(const float4*)(bw + lane * 8 + 4);
  float sum = 0.f, sq = 0.f;
#pragma unroll
  for (int j = 0; j < 8; ++j) { sum += xv[j]; sq += xv[j] * xv[j]; }
#pragma unroll
  for (int d = 1; d < 64; d <<= 1) {
    sum += __shfl_xor(sum, d);
    sq += __shfl_xor(sq, d);
  }
  float mean = sum * (1.f / 512.f);
  float var = sq * (1.f / 512.f) - mean * mean;
  float rstd = rsqrtf(var + 1e-5f);
  union { uint4 u; u16 h[8]; } ob;
#pragma unroll
  for (int j = 0; j < 8; ++j)
    ob.h[j] = f2bf((xv[j] - mean) * rstd * gv[j] + bv[j]);
  *(uint4*)(out + (size_t)row * 512 + lane * 8) = ob.u;
}

// ---------------------------------------------------------------------------
// GEMM: C[M][N] = A[M][K](bf16, row stride lda) * Bt[N][K](bf16, row stride ldb)^T
// Batched over blockIdx.z with element strides sA/sB/sC.
// EPI 1: QKV fused: bf16 = acc + bias(q|k|v per col>>9); cols>=1024 write
//        V TRANSPOSED into vtg[b][col-1024][row] (packed 8B stores)
// EPI 2: out bf16 = gelu(acc + bias)    (MLP1, tanh-form)
// EPI 3: out f32  = acc + bias + res    (Wo-proj, MLP2)
// EPI 4: out bf16 = acc / rowsum(A)     (PV; rowsum via ones-B MFMA)
// EPI 5: out bf16 = exp(acc * 1/sqrt(512))  (QK -> unnormalized softmax)
// 128x128 tile, BK=64, 256 threads (4 waves, 2x2), wave does 64x64 (4x4 frags).
// LDS: K-panel split [panel=k/32][128 rows][32 elems] (64B rows, conflict-min).
//   As[p*4096 + r*32 + c] = A[m0+r][k0 + p*32 + c]
// ---------------------------------------------------------------------------
template <int EPI>
__global__ __launch_bounds__(256, 2) void gemm_bt(const u16* __restrict__ A, int lda, size_t sA,
                                                  const u16* __restrict__ Bt, int ldb, size_t sB,
                                                  const float* __restrict__ bias,
                                                  const float* __restrict__ bias1,
                                                  const float* __restrict__ bias2,
                                                  const float* __restrict__ res,
                                                  u16* __restrict__ vtg,
                                                  void* __restrict__ out, int ldc, size_t sC,
                                                  int M, int N, int K) {
  __shared__ u16 As[128 * 64];
  __shared__ u16 Bs[128 * 64];
  const int tid = threadIdx.x;
  const int lane = tid & 63, w = tid >> 6;
  const int wr = w >> 1, wc = w & 1;
  const int m0 = blockIdx.x * 128, n0 = blockIdx.y * 128;
  const int lh = lane >> 4, ll = lane & 15;
  A += (size_t)blockIdx.z * sA;
  Bt += (size_t)blockIdx.z * sB;

  // staging: block t = w*4+j covers panel (t>>3), rows (t&7)*16 + (lane>>2),
  // elems (t>>3)*32 + (lane&3)*8; dest = linear 1024B at As/Bs + t*512
  const int srow = lane >> 2;          // 0..15
  const int scol = (lane & 3) * 8;     // 0,8,16,24
  const u16* ga = A + (size_t)(m0 + srow) * lda + scol;
  const u16* gb = Bt + (size_t)(n0 + srow) * ldb + scol;

  // all-ones B fragment for inline row-sum (EPI 4)
  bf16x8 ones;
#pragma unroll
  for (int j = 0; j < 8; ++j) ones[j] = (__bf16)1.0f;

  f32x4 acc[4][4] = {};
  f32x4 accs[4] = {};
  const int nk = K >> 6;
  for (int kt = 0; kt < nk; ++kt) {
    const int k0 = kt << 6;
#pragma unroll
    for (int j = 0; j < 4; ++j) {
      const int t = w * 4 + j;
      const int radd = (t & 7) * 16;
      const int kadd = (t >> 3) * 32;
      GLDS16(ga + (size_t)radd * lda + k0 + kadd, &As[t * 512]);
      GLDS16(gb + (size_t)radd * ldb + k0 + kadd, &Bs[t * 512]);
    }
    __syncthreads();
#pragma unroll
    for (int ks = 0; ks < 2; ++ks) {
      bf16x8 a[4], b[4];
#pragma unroll
      for (int m = 0; m < 4; ++m)
        a[m] = *(const bf16x8*)&As[ks * 4096 + (wr * 64 + m * 16 + ll) * 32 + lh * 8];
#pragma unroll
      for (int n = 0; n < 4; ++n)
        b[n] = *(const bf16x8*)&Bs[ks * 4096 + (wc * 64 + n * 16 + ll) * 32 + lh * 8];
#pragma unroll
      for (int m = 0; m < 4; ++m)
#pragma unroll
        for (int n = 0; n < 4; ++n)
          acc[m][n] = mfma16(a[m], b[n], acc[m][n]);
      if (EPI == 4) {
#pragma unroll
        for (int m = 0; m < 4; ++m) accs[m] = mfma16(a[m], ones, accs[m]);
      }
    }
    __syncthreads();
  }

  // epilogue (C/D layout: col = lane&15, row = (lane>>4)*4 + i, verified m89)
  u16* outh = (u16*)out + (size_t)blockIdx.z * sC;
  float* outf = (float*)out + (size_t)blockIdx.z * sC;
#pragma unroll
  for (int m = 0; m < 4; ++m) {
    int row = m0 + wr * 64 + m * 16 + lh * 4;
#pragma unroll
    for (int n = 0; n < 4; ++n) {
      int col = n0 + wc * 64 + n * 16 + ll;
      float bv = 0.f;
      if (EPI == 1) {
        const float* bp = (col < 512) ? bias : (col < 1024 ? bias1 : bias2);
        bv = bp[col & 511];
      } else if (EPI == 2 || EPI == 3) {
        bv = bias[col];
      }
      if (EPI == 1 && col >= 1024) {
        // V output: write transposed to vtg[b][col-1024][row..row+3]
        union { uint2 u; u16 h[4]; } pk;
#pragma unroll
        for (int i = 0; i < 4; ++i) pk.h[i] = f2bf(acc[m][n][i] + bv);
        const int b = row >> 12, brow = row & 4095;
        *(uint2*)&vtg[((size_t)(b * 512 + (col - 1024))) * 4096 + brow] = pk.u;
      } else {
#pragma unroll
        for (int i = 0; i < 4; ++i) {
          float v = acc[m][n][i] + bv;
          size_t idx = (size_t)(row + i) * ldc + col;
          if (EPI == 2) {
            // tanh-form gelu; max dev from erf-gelu ~3e-4 << bf16 ulp of m1
            float y = 0.7978845608028654f * (v + 0.044715f * v * v * v);
            v = v / (1.f + __expf(-2.f * y));
          }
          if (EPI == 4) v = v * (1.f / accs[m][i]);   // rowsum > 0 always
          if (EPI == 5) v = __expf(v * 0.044194173824159216f);  // 512^-0.5
          if (EPI == 3)
            outf[idx] = v + res[(size_t)blockIdx.z * sC + idx];
          else
            outh[idx] = f2bf(v);
        }
      }
    }
  }
}

// ---------------------------------------------------------------------------
extern "C" void kernel_launch(void* const* d_in, const int* in_sizes, int n_in,
                              void* d_out, int out_size, void* d_ws, size_t ws_size,
                              hipStream_t stream) {
  const float* x     = (const float*)d_in[0];
  const float* ln1g  = (const float*)d_in[1];
  const float* ln1b  = (const float*)d_in[2];
  const float* Wq    = (const float*)d_in[3];
  const float* bq    = (const float*)d_in[4];
  const float* Wk    = (const float*)d_in[5];
  const float* bk    = (const float*)d_in[6];
  const float* Wv    = (const float*)d_in[7];
  const float* bVv   = (const float*)d_in[8];
  const float* Wo    = (const float*)d_in[9];
  const float* bo    = (const float*)d_in[10];
  const float* ln2g  = (const float*)d_in[11];
  const float* ln2b  = (const float*)d_in[12];
  const float* W1    = (const float*)d_in[13];
  const float* b1    = (const float*)d_in[14];
  const float* W2    = (const float*)d_in[15];
  const float* b2    = (const float*)d_in[16];

  char* base = (char*)d_ws;
  u16* Wqkvt = (u16*)base;                      // [1536][512]
  u16* Wot   = Wqkvt + 786432;                  // [512][512]
  u16* W1t   = Wot + 262144;                    // [2048][512]
  u16* W2t   = W1t + 1048576;                   // [512][2048]
  u16* qkvb = (u16*)(base + (8ull << 20));      // [16384][1536] bf16 (V region unused)
  u16* Vt   = qkvb + (size_t)16384 * 1536;      // [4][512][4096] bf16
  u16* m1   = qkvb;                             // alias (qkv+Vt dead by MLP)
  u16* hb   = (u16*)(base + (72ull << 20));     // h/o/h2 [16384][512] bf16
  const size_t sco_off = 88ull << 20;
  u16* scores = (u16*)(base + sco_off);         // [nb][4096][4096] bf16 (exp-scores)
  float* x1 = (float*)scores;                   // alias (scores dead by Wo)

  const size_t S = 4096;
  const size_t per_b = S * S * 2;
  int nb = 1;
  if (ws_size >= sco_off + 4 * per_b) nb = 4;
  else if (ws_size >= sco_off + 2 * per_b) nb = 2;

  // all weight transposes in one launch
  prep_all<<<3072, 256, 0, stream>>>(Wq, Wk, Wv, Wo, W1, W2, Wqkvt, Wot, W1t, W2t);

  // h = LN1(x)
  ln_fwd<<<4096, 256, 0, stream>>>(x, ln1g, ln1b, hb);
  // qkv = h @ Wqkv + b; V written transposed straight into Vt
  gemm_bt<1><<<dim3(128, 12, 1), 256, 0, stream>>>(hb, 512, 0, Wqkvt, 512, 0,
                                                   bq, bk, bVv, nullptr, Vt,
                                                   qkvb, 1536, 0, 16384, 1536, 512);

  // attention, nb batches per chunk; softmax fused: QK writes exp(s*scale),
  // PV normalizes by inline row-sum.
  for (int b0 = 0; b0 < 4; b0 += nb) {
    int nz = (4 - b0) < nb ? (4 - b0) : nb;
    const u16* qk = qkvb + (size_t)b0 * S * 1536;
    // scores[z] = exp(Q @ K^T * scale)   (bf16, unnormalized)
    gemm_bt<5><<<dim3(32, 32, nz), 256, 0, stream>>>(qk, 1536, S * 1536, qk + 512, 1536, S * 1536,
                                                     nullptr, nullptr, nullptr, nullptr, nullptr,
                                                     scores, 4096, S * S, 4096, 4096, 512);
    // O[z] = (P~ @ V) / rowsum(P~)
    gemm_bt<4><<<dim3(32, 4, nz), 256, 0, stream>>>(scores, 4096, S * S,
                                                    Vt + (size_t)b0 * 512 * S, 4096, 512 * S,
                                                    nullptr, nullptr, nullptr, nullptr, nullptr,
                                                    hb + (size_t)b0 * S * 512, 512, S * 512,
                                                    4096, 512, 4096);
  }

  // x1 = x + o @ Wo + bo
  gemm_bt<3><<<dim3(128, 4, 1), 256, 0, stream>>>(hb, 512, 0, Wot, 512, 0,
                                                  bo, nullptr, nullptr, x, nullptr,
                                                  x1, 512, 0, 16384, 512, 512);
  // h2 = LN2(x1)
  ln_fwd<<<4096, 256, 0, stream>>>(x1, ln2g, ln2b, hb);
  // m1 = gelu(h2 @ W1 + b1)
  gemm_bt<2><<<dim3(128, 16, 1), 256, 0, stream>>>(hb, 512, 0, W1t, 512, 0,
                                                   b1, nullptr, nullptr, nullptr, nullptr,
                                                   m1, 2048, 0, 16384, 2048, 512);
  // out = x1 + m1 @ W2 + b2
  gemm_bt<3><<<dim3(128, 4, 1), 256, 0, stream>>>(m1, 2048, 0, W2t, 2048, 0,
                                                  b2, nullptr, nullptr, x1, nullptr,
                                                  (float*)d_out, 512, 0, 16384, 512, 2048);
}